// Round 10
// baseline (103.443 us; speedup 1.0000x reference)
//
#include <hip/hip_runtime.h>
#include <hip/hip_bf16.h>
#include <hip/hip_fp8.h>

// Problem constants (fixed by reference): N=10000, D=128, E=640000.
// r8 decomposition: harness ~69 us fixed + p1 + agg. r9 (NB=128): 94.1 us.
// This round: (1) inline first-2 srcs into 8-B combo entries (91% of
// segments skip bins), (2) 16-B gather (64 rows/trip -> mean degree 64
// finishes in ONE latency trip).
#define NB    128      // sort blocks; each owns E/NB edges (dispatched first)
#define EPB   5000     // edges per sort block
#define NPAD  10240    // scan width: 256 threads * 40 nodes
#define NPT   40       // nodes per thread in scan
#define NGEMM 625      // gemm role blocks (10000/16)
#define LCAP  1024     // per-wave src-list capacity (max degree ~110 for this input)
#define SMEM_BYTES 30496  // sort: h 20480 + sorted 10000 + wsum 16 (gemm uses 8448)

typedef __bf16 bf16_8 __attribute__((ext_vector_type(8)));
typedef float f32_2 __attribute__((ext_vector_type(2)));
typedef float f32_4 __attribute__((ext_vector_type(4)));
typedef float f32_8 __attribute__((ext_vector_type(8)));

// ---------------------------------------------------------------------------
// gemm role: z = x @ W^T (bf16 MFMA); C-tile staged in LDS so the zb (bf16)
// and zb8 (fp8 e4m3) outputs are written with coalesced 16B/8B stores.
// (verified r1/r2/r4/r5/r9 - unchanged)
// ---------------------------------------------------------------------------
__device__ __forceinline__ void gemm_role(unsigned char* smem, int bx,
    const float* __restrict__ x, const float* __restrict__ W,
    __hip_bfloat16* __restrict__ zb, unsigned char* __restrict__ zb8) {
  float* ctile = (float*)smem;  // [16][132] padded stride
  const int rowbase = bx * 16;
  const int wid = threadIdx.x >> 6;
  const int lane = threadIdx.x & 63;
  const int m16 = lane & 15;
  const int quad = lane >> 4;

  union { bf16_8 v; __hip_bfloat16 h8[8]; } ac[4];
  const float* arow = x + (size_t)(rowbase + m16) * 128 + quad * 8;
#pragma unroll
  for (int kk = 0; kk < 4; ++kk) {
    f32_8 af = *(const f32_8*)(arow + kk * 32);
#pragma unroll
    for (int j = 0; j < 8; ++j) ac[kk].h8[j] = __float2bfloat16(af[j]);
  }
#pragma unroll
  for (int ct = 0; ct < 2; ++ct) {
    int colbase = wid * 32 + ct * 16;
    const float* brow = W + (size_t)(colbase + m16) * 128 + quad * 8;
    f32_4 c = {0.f, 0.f, 0.f, 0.f};
#pragma unroll
    for (int kk = 0; kk < 4; ++kk) {
      f32_8 bf = *(const f32_8*)(brow + kk * 32);
      union { bf16_8 v; __hip_bfloat16 h8[8]; } bc;
#pragma unroll
      for (int j = 0; j < 8; ++j) bc.h8[j] = __float2bfloat16(bf[j]);
      c = __builtin_amdgcn_mfma_f32_16x16x32_bf16(ac[kk].v, bc.v, c, 0, 0, 0);
    }
#pragma unroll
    for (int r = 0; r < 4; ++r)
      ctile[(quad * 4 + r) * 132 + colbase + m16] = c[r];
  }
  __syncthreads();

  // coalesced write-out: thread t -> row t>>4, 8 features at (t&15)*8
  const int row = threadIdx.x >> 4;
  const int cs = (threadIdx.x & 15) * 8;
  const float* src = ctile + row * 132 + cs;
  f32_4 a0 = *(const f32_4*)(src);
  f32_4 a1 = *(const f32_4*)(src + 4);
  union { uint4 u; __hip_bfloat16 h[8]; } hb;
  union { uint2 u; unsigned char c[8]; } q8;
#pragma unroll
  for (int j = 0; j < 4; ++j) {
    hb.h[j] = __float2bfloat16(a0[j]);
    hb.h[4 + j] = __float2bfloat16(a1[j]);
    q8.c[j] = __hip_fp8_e4m3(a0[j]).__x;
    q8.c[4 + j] = __hip_fp8_e4m3(a1[j]).__x;
  }
  *(uint4*)(zb + (size_t)(rowbase + row) * 128 + cs) = hb.u;   // 16 B
  *(uint2*)(zb8 + (size_t)(rowbase + row) * 128 + cs) = q8.u;  // 8 B
}

// ---------------------------------------------------------------------------
// sort role: counting-sort EPB=5000 edges by dst (LDS only), NB=128 (the
// r9-verified geometry). Pass A/C paired loads (verified r2/r5/r9).
// Pass D (mechanics verified r3/r4): emit 8-B combo entries with the first
// TWO sources inlined: { s0|s1<<16, (count<<16)|offset } -> 91% of segments
// (lambda=0.5) never touch bins in k_agg.
// ---------------------------------------------------------------------------
__device__ __forceinline__ void sort_role(unsigned char* smem, int b,
    const int* __restrict__ ei, int E,
    unsigned short* __restrict__ bins, uint2* __restrict__ combo) {
  int* h = (int*)smem;                                       // 20480 B
  unsigned short* sorted = (unsigned short*)(smem + 20480);  // 10000 B
  int* wsum = (int*)(smem + 30480);                          // 16 B

  const int t = threadIdx.x;
  const int4* src4 = (const int4*)(ei) + b * (EPB / 4);
  const int4* dst4 = (const int4*)(ei + E) + b * (EPB / 4);

  for (int i = t; i < NPAD / 2; i += 256) h[i] = 0;
  __syncthreads();

  // Pass A: histogram (packed-pair u16 LDS atomics), paired loads.
#pragma unroll
  for (int k = 0; k < 2; ++k) {
    int i0 = t + k * 512;
    int4 d0 = dst4[i0];
    int4 d1 = dst4[i0 + 256];
    atomicAdd(&h[d0.x >> 1], 1 << ((d0.x & 1) * 16));
    atomicAdd(&h[d0.y >> 1], 1 << ((d0.y & 1) * 16));
    atomicAdd(&h[d0.z >> 1], 1 << ((d0.z & 1) * 16));
    atomicAdd(&h[d0.w >> 1], 1 << ((d0.w & 1) * 16));
    atomicAdd(&h[d1.x >> 1], 1 << ((d1.x & 1) * 16));
    atomicAdd(&h[d1.y >> 1], 1 << ((d1.y & 1) * 16));
    atomicAdd(&h[d1.z >> 1], 1 << ((d1.z & 1) * 16));
    atomicAdd(&h[d1.w >> 1], 1 << ((d1.w & 1) * 16));
  }
  if (t < 226) {
    int4 d = dst4[1024 + t];
    atomicAdd(&h[d.x >> 1], 1 << ((d.x & 1) * 16));
    atomicAdd(&h[d.y >> 1], 1 << ((d.y & 1) * 16));
    atomicAdd(&h[d.z >> 1], 1 << ((d.z & 1) * 16));
    atomicAdd(&h[d.w >> 1], 1 << ((d.w & 1) * 16));
  }
  __syncthreads();

  // Pass B: block-wide exclusive scan; packed cursors in h, cpack in regs.
  int raw[NPT];
  const int lo = t * NPT;  // even
  int sum = 0;
#pragma unroll
  for (int j = 0; j < NPT; j += 2) {
    int pair = h[(lo + j) >> 1];
    raw[j] = pair & 0xFFFF;
    raw[j + 1] = (pair >> 16) & 0xFFFF;
    sum += raw[j] + raw[j + 1];
  }
  int incl = sum;
#pragma unroll
  for (int off = 1; off < 64; off <<= 1) {
    int v = __shfl_up(incl, off);
    if ((t & 63) >= off) incl += v;
  }
  if ((t & 63) == 63) wsum[t >> 6] = incl;
  __syncthreads();
  int wb = 0;
  for (int w = 0; w < (t >> 6); ++w) wb += wsum[w];
  int run = wb + incl - sum;  // block-wide exclusive prefix for this range

  unsigned int cpack[NPT];
#pragma unroll
  for (int j = 0; j < NPT; j += 2) {
    int r0 = run; run += raw[j];
    int r1 = run; run += raw[j + 1];
    h[(lo + j) >> 1] = (r1 << 16) | r0;  // packed cursors for Pass C
    cpack[j]     = ((unsigned)raw[j] << 16) | (unsigned)r0;
    cpack[j + 1] = ((unsigned)raw[j + 1] << 16) | (unsigned)r1;
  }
  __syncthreads();

  // Pass C: rank via packed-pair atomic rtn, scatter into LDS; paired loads.
#pragma unroll
  for (int k = 0; k < 2; ++k) {
    int i0 = t + k * 512;
    int4 s0 = src4[i0];
    int4 d0 = dst4[i0];
    int4 s1 = src4[i0 + 256];
    int4 d1 = dst4[i0 + 256];
    int ss[8] = {s0.x, s0.y, s0.z, s0.w, s1.x, s1.y, s1.z, s1.w};
    int dd[8] = {d0.x, d0.y, d0.z, d0.w, d1.x, d1.y, d1.z, d1.w};
#pragma unroll
    for (int u = 0; u < 8; ++u) {
      int nn = dd[u];
      int sh = (nn & 1) * 16;
      int pos = (atomicAdd(&h[nn >> 1], 1 << sh) >> sh) & 0xFFFF;
      sorted[pos] = (unsigned short)ss[u];
    }
  }
  if (t < 226) {
    int4 s = src4[1024 + t];
    int4 d = dst4[1024 + t];
    int ss[4] = {s.x, s.y, s.z, s.w};
    int dd[4] = {d.x, d.y, d.z, d.w};
#pragma unroll
    for (int u = 0; u < 4; ++u) {
      int nn = dd[u];
      int sh = (nn & 1) * 16;
      int pos = (atomicAdd(&h[nn >> 1], 1 << sh) >> sh) & 0xFFFF;
      sorted[pos] = (unsigned short)ss[u];
    }
  }
  __syncthreads();

  // Pass D: combo row with first-2 sources inlined (8-B stores; LDS reads)
  uint2* crow = combo + (size_t)b * NPAD + lo;
#pragma unroll
  for (int j = 0; j < NPT; ++j) {
    unsigned int hi = cpack[j];
    int c = (int)(hi >> 16);
    int o = (int)(hi & 0xFFFF);
    unsigned int s0 = (c > 0) ? (unsigned int)sorted[o] : 0u;
    unsigned int s1 = (c > 1) ? (unsigned int)sorted[o + 1] : 0u;
    crow[j] = make_uint2(s0 | (s1 << 16), hi);
  }

  // stream out bins (only count>=3 tails read it; cheap: 10 KB)
  unsigned int* outb = (unsigned int*)(bins + (size_t)b * EPB);
  const unsigned int* s32 = (const unsigned int*)sorted;
  for (int i = t; i < EPB / 2; i += 256) outb[i] = s32[i];
}

__global__ void __launch_bounds__(256) k_phase1(
    const float* __restrict__ x, const int* __restrict__ ei,
    const float* __restrict__ W,
    __hip_bfloat16* __restrict__ zb, unsigned char* __restrict__ zb8,
    unsigned short* __restrict__ bins, uint2* __restrict__ combo, int E) {
  __shared__ __align__(16) unsigned char smem[SMEM_BYTES];
  // sort blocks FIRST: they are the phase-1 critical path
  if (blockIdx.x < NB) sort_role(smem, blockIdx.x, ei, E, bins, combo);
  else gemm_role(smem, blockIdx.x - NB, x, W, zb, zb8);
}

// ---------------------------------------------------------------------------
// k_agg: block = 4 nodes (one per wave), NB=128 -> two segments per lane.
//  - COALESCED transpose (r6 lesson: per-lane direct combo reads regressed):
//    256 threads each load one uint4 = 2 adjacent uint2 combo entries.
//  - s0,s1 per segment arrive inline (91% of segments skip bins entirely);
//    bins only for c>=3 tails.
//  - wave-local __shfl_up scan; per-wave list; ONE block barrier (r5/r9).
//  - 16-B gather (verified r1): 8 lanes x uint4 per 128-B row, 64 rows in
//    flight -> mean degree 64 completes in ONE latency trip.
//  NO min-waves launch bound (r2 lesson: reg cap -> spill storm).
// ---------------------------------------------------------------------------
__global__ void __launch_bounds__(256) k_agg(
    const uint2* __restrict__ combo, const unsigned short* __restrict__ bins,
    const unsigned char* __restrict__ zb8, const __hip_bfloat16* __restrict__ zb,
    const float* __restrict__ bias, float* __restrict__ out, int N) {
  __shared__ uint2 trans[4][128];             // 4 KB
  __shared__ unsigned short list[4][LCAP];    // 8 KB

  const int t = threadIdx.x;
  const int wid = t >> 6;
  const int lane = t & 63;
  const int n0 = blockIdx.x * 4;

  // transpose: thread t loads combo[row=t>>1][n0 + 2*(t&1) .. +1] (16 B)
  {
    const int row = t >> 1;
    const int k2 = (t & 1) * 2;
    uint4 cm = *(const uint4*)(combo + (size_t)row * NPAD + n0 + k2);
    trans[k2][row] = make_uint2(cm.x, cm.y);
    trans[k2 + 1][row] = make_uint2(cm.z, cm.w);
  }
  __syncthreads();   // the only block-wide barrier

  const int n = n0 + wid;
  uint2 e0 = trans[wid][lane];         // segment: sort block = lane
  uint2 e1 = trans[wid][lane + 64];    // segment: sort block = lane+64
  const int c0 = (int)(e0.y >> 16), o0 = (int)(e0.y & 0xFFFF);
  const int c1 = (int)(e1.y >> 16), o1 = (int)(e1.y & 0xFFFF);
  const int c = c0 + c1;

  // wave-local exclusive scan of c -> slot p; m = wave total (true degree)
  int incl = c;
#pragma unroll
  for (int off = 1; off < 64; off <<= 1) {
    int v = __shfl_up(incl, off);
    if (lane >= off) incl += v;
  }
  const int m = __shfl(incl, 63);
  const int p = incl - c;

  {
    unsigned short* L = list[wid];
    // segment 0: first 2 sources inline, bins only for c0>=3 (9%)
    if (c0 > 0 && p < LCAP) L[p] = (unsigned short)(e0.x & 0xFFFF);
    if (c0 > 1 && p + 1 < LCAP) L[p + 1] = (unsigned short)(e0.x >> 16);
    if (c0 > 2) {
      const unsigned short* bk = bins + (size_t)lane * EPB + o0;
      for (int j = 2; j < c0; ++j)
        if (p + j < LCAP) L[p + j] = bk[j];
    }
    const int q = p + c0;
    if (c1 > 0 && q < LCAP) L[q] = (unsigned short)(e1.x & 0xFFFF);
    if (c1 > 1 && q + 1 < LCAP) L[q + 1] = (unsigned short)(e1.x >> 16);
    if (c1 > 2) {
      const unsigned short* bk = bins + (size_t)(lane + 64) * EPB + o1;
      for (int j = 2; j < c1; ++j)
        if (q + j < LCAP) L[q + j] = bk[j];
    }
  }
  // no barrier: list[wid] is produced and consumed by this wave only
  // (compiler orders the LDS write->read via lgkmcnt)

  const int g = lane >> 3;    // row-group (8 groups)
  const int sub = lane & 7;   // 16-B chunk of the 128-B fp8 row
  int mm = m < LCAP ? m : LCAP;
  const unsigned short* L = list[wid];
  const unsigned char* z8base = zb8 + sub * 16;

  float acc[16];
#pragma unroll
  for (int k = 0; k < 16; ++k) acc[k] = 0.f;

  for (int e = 0; e < mm; e += 64) {
    // phase 1: issue up to 8 independent 16-B fp8 row loads (64 rows/trip)
    uint4 v[8];
#pragma unroll
    for (int u = 0; u < 8; ++u) {
      int idx = e + u * 8 + g;
      v[u] = make_uint4(0u, 0u, 0u, 0u);
      if (idx < mm) {
        int s = L[idx];
        v[u] = *(const uint4*)(z8base + (size_t)s * 128);
      }
    }
    // phase 2: packed HW fp8->f32 decode + accumulate (0x00 decodes to 0.0)
#pragma unroll
    for (int u = 0; u < 8; ++u) {
      f32_2 p01 = __builtin_amdgcn_cvt_pk_f32_fp8((int)v[u].x, false);
      f32_2 p23 = __builtin_amdgcn_cvt_pk_f32_fp8((int)v[u].x, true);
      f32_2 p45 = __builtin_amdgcn_cvt_pk_f32_fp8((int)v[u].y, false);
      f32_2 p67 = __builtin_amdgcn_cvt_pk_f32_fp8((int)v[u].y, true);
      f32_2 p89 = __builtin_amdgcn_cvt_pk_f32_fp8((int)v[u].z, false);
      f32_2 pab = __builtin_amdgcn_cvt_pk_f32_fp8((int)v[u].z, true);
      f32_2 pcd = __builtin_amdgcn_cvt_pk_f32_fp8((int)v[u].w, false);
      f32_2 pef = __builtin_amdgcn_cvt_pk_f32_fp8((int)v[u].w, true);
      acc[0] += p01[0];  acc[1] += p01[1];  acc[2] += p23[0];  acc[3] += p23[1];
      acc[4] += p45[0];  acc[5] += p45[1];  acc[6] += p67[0];  acc[7] += p67[1];
      acc[8] += p89[0];  acc[9] += p89[1];  acc[10] += pab[0]; acc[11] += pab[1];
      acc[12] += pcd[0]; acc[13] += pcd[1]; acc[14] += pef[0]; acc[15] += pef[1];
    }
  }
#pragma unroll
  for (int k = 0; k < 16; ++k) {
    acc[k] += __shfl_xor(acc[k], 8);
    acc[k] += __shfl_xor(acc[k], 16);
    acc[k] += __shfl_xor(acc[k], 32);
  }

  if (g == 0 && n < N) {
    float inv = 1.f / (float)(m > 0 ? m : 1);
    const __hip_bfloat16* znp = zb + (size_t)n * 128 + sub * 16;
    bf16_8 z0 = *(const bf16_8*)znp;
    bf16_8 z1 = *(const bf16_8*)(znp + 8);
    const float* bp = bias + sub * 16;
    f32_8 b0 = *(const f32_8*)bp;
    f32_8 b1 = *(const f32_8*)(bp + 8);
    float r[16];
#pragma unroll
    for (int k = 0; k < 8; ++k) {
      float v2 = acc[k] * inv + (float)z0[k] + b0[k];
      r[k] = v2 > 0.f ? v2 : 0.f;
    }
#pragma unroll
    for (int k = 0; k < 8; ++k) {
      float v2 = acc[8 + k] * inv + (float)z1[k] + b1[k];
      r[8 + k] = v2 > 0.f ? v2 : 0.f;
    }
    float* o2 = out + (size_t)n * 128 + sub * 16;
    *(float4*)(o2)      = make_float4(r[0], r[1], r[2], r[3]);
    *(float4*)(o2 + 4)  = make_float4(r[4], r[5], r[6], r[7]);
    *(float4*)(o2 + 8)  = make_float4(r[8], r[9], r[10], r[11]);
    *(float4*)(o2 + 12) = make_float4(r[12], r[13], r[14], r[15]);
  }
}

// ---------------------------------------------------------------------------
extern "C" void kernel_launch(void* const* d_in, const int* in_sizes, int n_in,
                              void* d_out, int out_size, void* d_ws, size_t ws_size,
                              hipStream_t stream) {
  const float* x = (const float*)d_in[0];
  const int* ei = (const int*)d_in[1];
  const float* W = (const float*)d_in[2];
  const float* b = (const float*)d_in[3];
  float* out = (float*)d_out;

  const int N = in_sizes[0] / 128;  // 10000
  const int E = in_sizes[1] / 2;    // 640000 (= NB * EPB)

  char* ws = (char*)d_ws;
  size_t off = 0;
  auto carve = [&](size_t bytes) {
    void* p = ws + off;
    off = (off + bytes + 255) & ~(size_t)255;
    return p;
  };
  __hip_bfloat16* zb = (__hip_bfloat16*)carve((size_t)N * 128 * 2);     // 2.56 MB
  unsigned char* zb8 = (unsigned char*)carve((size_t)N * 128);          // 1.28 MB
  unsigned short* bins = (unsigned short*)carve((size_t)NB * EPB * 2);  // 1.28 MB
  uint2* combo = (uint2*)carve((size_t)NB * NPAD * 8);                  // 10.49 MB

  // 1) fused: per-block counting sort (128 blocks, first) || z = x@W^T
  k_phase1<<<NB + NGEMM, 256, 0, stream>>>(x, ei, W, zb, zb8, bins, combo, E);
  // 2) inline-src segment-sum + 16-B fp8 gather + /deg + z[n] + bias + relu
  k_agg<<<N / 4, 256, 0, stream>>>(combo, bins, zb8, zb, b, out, N);
}

// Round 11
// 94.548 us; speedup vs baseline: 1.0941x; 1.0941x over previous
//
#include <hip/hip_runtime.h>
#include <hip/hip_bf16.h>
#include <hip/hip_fp8.h>

// Problem constants (fixed by reference): N=10000, D=128, E=640000.
// Decomposition (r7/r8 A/B): harness ~69 us fixed + p1 ~10 us + agg ~15 us.
// r9 (NB=128) = 94.1 us best. r10 bundle regressed (reverted).
// This round: r9 + ONE change - hoist epilogue zb/bias loads above the
// gather loop in k_agg (hide their L2 latency under the gather trips).
#define NB    128      // sort blocks; each owns E/NB edges (dispatched first)
#define EPB   5000     // edges per sort block
#define NPAD  10240    // scan width: 256 threads * 40 nodes
#define NPT   40       // nodes per thread in scan
#define NGEMM 625      // gemm role blocks (10000/16)
#define LCAP  1024     // per-wave src-list capacity (max degree ~110 for this input)
#define SMEM_BYTES 30496  // sort: h 20480 + sorted 10000 + wsum 16 (gemm uses 8448)

typedef __bf16 bf16_8 __attribute__((ext_vector_type(8)));
typedef float f32_2 __attribute__((ext_vector_type(2)));
typedef float f32_4 __attribute__((ext_vector_type(4)));
typedef float f32_8 __attribute__((ext_vector_type(8)));

// ---------------------------------------------------------------------------
// gemm role: z = x @ W^T (bf16 MFMA); C-tile staged in LDS so the zb (bf16)
// and zb8 (fp8 e4m3) outputs are written with coalesced 16B/8B stores.
// (verified r1/r2/r4/r5/r9 - unchanged)
// ---------------------------------------------------------------------------
__device__ __forceinline__ void gemm_role(unsigned char* smem, int bx,
    const float* __restrict__ x, const float* __restrict__ W,
    __hip_bfloat16* __restrict__ zb, unsigned char* __restrict__ zb8) {
  float* ctile = (float*)smem;  // [16][132] padded stride
  const int rowbase = bx * 16;
  const int wid = threadIdx.x >> 6;
  const int lane = threadIdx.x & 63;
  const int m16 = lane & 15;
  const int quad = lane >> 4;

  union { bf16_8 v; __hip_bfloat16 h8[8]; } ac[4];
  const float* arow = x + (size_t)(rowbase + m16) * 128 + quad * 8;
#pragma unroll
  for (int kk = 0; kk < 4; ++kk) {
    f32_8 af = *(const f32_8*)(arow + kk * 32);
#pragma unroll
    for (int j = 0; j < 8; ++j) ac[kk].h8[j] = __float2bfloat16(af[j]);
  }
#pragma unroll
  for (int ct = 0; ct < 2; ++ct) {
    int colbase = wid * 32 + ct * 16;
    const float* brow = W + (size_t)(colbase + m16) * 128 + quad * 8;
    f32_4 c = {0.f, 0.f, 0.f, 0.f};
#pragma unroll
    for (int kk = 0; kk < 4; ++kk) {
      f32_8 bf = *(const f32_8*)(brow + kk * 32);
      union { bf16_8 v; __hip_bfloat16 h8[8]; } bc;
#pragma unroll
      for (int j = 0; j < 8; ++j) bc.h8[j] = __float2bfloat16(bf[j]);
      c = __builtin_amdgcn_mfma_f32_16x16x32_bf16(ac[kk].v, bc.v, c, 0, 0, 0);
    }
#pragma unroll
    for (int r = 0; r < 4; ++r)
      ctile[(quad * 4 + r) * 132 + colbase + m16] = c[r];
  }
  __syncthreads();

  // coalesced write-out: thread t -> row t>>4, 8 features at (t&15)*8
  const int row = threadIdx.x >> 4;
  const int cs = (threadIdx.x & 15) * 8;
  const float* src = ctile + row * 132 + cs;
  f32_4 a0 = *(const f32_4*)(src);
  f32_4 a1 = *(const f32_4*)(src + 4);
  union { uint4 u; __hip_bfloat16 h[8]; } hb;
  union { uint2 u; unsigned char c[8]; } q8;
#pragma unroll
  for (int j = 0; j < 4; ++j) {
    hb.h[j] = __float2bfloat16(a0[j]);
    hb.h[4 + j] = __float2bfloat16(a1[j]);
    q8.c[j] = __hip_fp8_e4m3(a0[j]).__x;
    q8.c[4 + j] = __hip_fp8_e4m3(a1[j]).__x;
  }
  *(uint4*)(zb + (size_t)(rowbase + row) * 128 + cs) = hb.u;   // 16 B
  *(uint2*)(zb8 + (size_t)(rowbase + row) * 128 + cs) = q8.u;  // 8 B
}

// ---------------------------------------------------------------------------
// sort role: counting-sort EPB=5000 edges by dst (LDS only), NB=128.
// HALF the per-block LDS-atomic work of the NB=64 version (the measured
// phase-1 pole). Pass A/C paired loads (verified r2/r5/r9).
// ---------------------------------------------------------------------------
__device__ __forceinline__ void sort_role(unsigned char* smem, int b,
    const int* __restrict__ ei, int E,
    unsigned short* __restrict__ bins, unsigned int* __restrict__ combo) {
  int* h = (int*)smem;                                       // 20480 B
  unsigned short* sorted = (unsigned short*)(smem + 20480);  // 10000 B
  int* wsum = (int*)(smem + 30480);                          // 16 B

  const int t = threadIdx.x;
  const int4* src4 = (const int4*)(ei) + b * (EPB / 4);
  const int4* dst4 = (const int4*)(ei + E) + b * (EPB / 4);

  for (int i = t; i < NPAD / 2; i += 256) h[i] = 0;
  __syncthreads();

  // Pass A: histogram (packed-pair u16 LDS atomics), paired loads.
#pragma unroll
  for (int k = 0; k < 2; ++k) {
    int i0 = t + k * 512;
    int4 d0 = dst4[i0];
    int4 d1 = dst4[i0 + 256];
    atomicAdd(&h[d0.x >> 1], 1 << ((d0.x & 1) * 16));
    atomicAdd(&h[d0.y >> 1], 1 << ((d0.y & 1) * 16));
    atomicAdd(&h[d0.z >> 1], 1 << ((d0.z & 1) * 16));
    atomicAdd(&h[d0.w >> 1], 1 << ((d0.w & 1) * 16));
    atomicAdd(&h[d1.x >> 1], 1 << ((d1.x & 1) * 16));
    atomicAdd(&h[d1.y >> 1], 1 << ((d1.y & 1) * 16));
    atomicAdd(&h[d1.z >> 1], 1 << ((d1.z & 1) * 16));
    atomicAdd(&h[d1.w >> 1], 1 << ((d1.w & 1) * 16));
  }
  if (t < 226) {
    int4 d = dst4[1024 + t];
    atomicAdd(&h[d.x >> 1], 1 << ((d.x & 1) * 16));
    atomicAdd(&h[d.y >> 1], 1 << ((d.y & 1) * 16));
    atomicAdd(&h[d.z >> 1], 1 << ((d.z & 1) * 16));
    atomicAdd(&h[d.w >> 1], 1 << ((d.w & 1) * 16));
  }
  __syncthreads();

  // Pass B: block-wide exclusive scan; emit packed cursors + combo row.
  int raw[NPT];
  const int lo = t * NPT;  // even
  int sum = 0;
#pragma unroll
  for (int j = 0; j < NPT; j += 2) {
    int pair = h[(lo + j) >> 1];
    raw[j] = pair & 0xFFFF;
    raw[j + 1] = (pair >> 16) & 0xFFFF;
    sum += raw[j] + raw[j + 1];
  }
  int incl = sum;
#pragma unroll
  for (int off = 1; off < 64; off <<= 1) {
    int v = __shfl_up(incl, off);
    if ((t & 63) >= off) incl += v;
  }
  if ((t & 63) == 63) wsum[t >> 6] = incl;
  __syncthreads();
  int wb = 0;
  for (int w = 0; w < (t >> 6); ++w) wb += wsum[w];
  int run = wb + incl - sum;  // block-wide exclusive prefix for this range

  unsigned int cpack[NPT];
#pragma unroll
  for (int j = 0; j < NPT; j += 2) {
    int r0 = run; run += raw[j];
    int r1 = run; run += raw[j + 1];
    h[(lo + j) >> 1] = (r1 << 16) | r0;  // packed cursors for Pass C
    cpack[j]     = ((unsigned)raw[j] << 16) | (unsigned)r0;
    cpack[j + 1] = ((unsigned)raw[j + 1] << 16) | (unsigned)r1;
  }
  __syncthreads();

  // combo row write: fully coalesced (10 x uint4 per thread)
  unsigned int* crow = combo + (size_t)b * NPAD + lo;
#pragma unroll
  for (int j = 0; j < NPT; j += 4)
    *(uint4*)(crow + j) = make_uint4(cpack[j], cpack[j+1], cpack[j+2], cpack[j+3]);

  // Pass C: rank via packed-pair atomic rtn, scatter into LDS; paired loads.
#pragma unroll
  for (int k = 0; k < 2; ++k) {
    int i0 = t + k * 512;
    int4 s0 = src4[i0];
    int4 d0 = dst4[i0];
    int4 s1 = src4[i0 + 256];
    int4 d1 = dst4[i0 + 256];
    int ss[8] = {s0.x, s0.y, s0.z, s0.w, s1.x, s1.y, s1.z, s1.w};
    int dd[8] = {d0.x, d0.y, d0.z, d0.w, d1.x, d1.y, d1.z, d1.w};
#pragma unroll
    for (int u = 0; u < 8; ++u) {
      int nn = dd[u];
      int sh = (nn & 1) * 16;
      int pos = (atomicAdd(&h[nn >> 1], 1 << sh) >> sh) & 0xFFFF;
      sorted[pos] = (unsigned short)ss[u];
    }
  }
  if (t < 226) {
    int4 s = src4[1024 + t];
    int4 d = dst4[1024 + t];
    int ss[4] = {s.x, s.y, s.z, s.w};
    int dd[4] = {d.x, d.y, d.z, d.w};
#pragma unroll
    for (int u = 0; u < 4; ++u) {
      int nn = dd[u];
      int sh = (nn & 1) * 16;
      int pos = (atomicAdd(&h[nn >> 1], 1 << sh) >> sh) & 0xFFFF;
      sorted[pos] = (unsigned short)ss[u];
    }
  }
  __syncthreads();

  // stream out coalesced (5000 ushort = 2500 uint)
  unsigned int* outb = (unsigned int*)(bins + (size_t)b * EPB);
  const unsigned int* s32 = (const unsigned int*)sorted;
  for (int i = t; i < EPB / 2; i += 256) outb[i] = s32[i];
}

__global__ void __launch_bounds__(256) k_phase1(
    const float* __restrict__ x, const int* __restrict__ ei,
    const float* __restrict__ W,
    __hip_bfloat16* __restrict__ zb, unsigned char* __restrict__ zb8,
    unsigned short* __restrict__ bins, unsigned int* __restrict__ combo, int E) {
  __shared__ __align__(16) unsigned char smem[SMEM_BYTES];
  // sort blocks FIRST: they are the phase-1 critical path
  if (blockIdx.x < NB) sort_role(smem, blockIdx.x, ei, E, bins, combo);
  else gemm_role(smem, blockIdx.x - NB, x, W, zb, zb8);
}

// ---------------------------------------------------------------------------
// k_agg: block = 4 nodes (one per wave), NB=128 -> two segments per lane
// (r9-verified structure). ONE change vs r9: the epilogue operands (zb row,
// bias) are loaded BEFORE the gather loop, so their ~L2 latency hides under
// the gather trips instead of being exposed serially at the chain tail.
// VGPR +12 (~52 total, still < 64 -> occupancy unchanged).
// NO min-waves launch bound (r2 lesson).
// ---------------------------------------------------------------------------
__global__ void __launch_bounds__(256) k_agg(
    const unsigned int* __restrict__ combo, const unsigned short* __restrict__ bins,
    const unsigned char* __restrict__ zb8, const __hip_bfloat16* __restrict__ zb,
    const float* __restrict__ bias, float* __restrict__ out, int N) {
  __shared__ unsigned int trans[4][128];      // 2 KB
  __shared__ unsigned short list[4][LCAP];    // 8 KB

  const int t = threadIdx.x;
  const int wid = t >> 6;
  const int lane = t & 63;
  const int n0 = blockIdx.x * 4;

  if (t < 128) {
    uint4 cm = *(const uint4*)(combo + (size_t)t * NPAD + n0);
    trans[0][t] = cm.x; trans[1][t] = cm.y; trans[2][t] = cm.z; trans[3][t] = cm.w;
  }
  __syncthreads();   // the only block-wide barrier

  const int n = n0 + wid;
  const int g = lane >> 4;    // row-group (4 groups)
  const int sub = lane & 15;  // 8-B chunk of the 128-B fp8 row

  // HOISTED epilogue operands: issue now, consumed after the gather loop.
  // Oldest in the VMEM queue -> complete under the gather trips for free.
  bf16_8 zn = {};
  f32_8 bv = {};
  if (g == 0 && n < N) {
    zn = *(const bf16_8*)(zb + (size_t)n * 128 + sub * 8);
    bv = *(const f32_8*)(bias + sub * 8);
  }

  unsigned int cc0 = trans[wid][lane];
  unsigned int cc1 = trans[wid][lane + 64];
  const int c0 = (int)(cc0 >> 16), o0 = (int)(cc0 & 0xFFFF);
  const int c1 = (int)(cc1 >> 16), o1 = (int)(cc1 & 0xFFFF);
  const int c = c0 + c1;

  // wave-local exclusive scan of c -> slot p; m = wave total (true degree)
  int incl = c;
#pragma unroll
  for (int off = 1; off < 64; off <<= 1) {
    int v = __shfl_up(incl, off);
    if (lane >= off) incl += v;
  }
  const int m = __shfl(incl, 63);
  const int p = incl - c;

  {
    unsigned short* L = list[wid];
    // segment 0 (sort block = lane), lambda=0.5
    const unsigned short* bk0 = bins + (size_t)lane * EPB + o0;
    // segment 1 (sort block = lane+64)
    const unsigned short* bk1 = bins + (size_t)(lane + 64) * EPB + o1;
    unsigned short a0 = 0, a1 = 0, b0 = 0, b1 = 0;
    if (c0 > 0) a0 = bk0[0];           // independent guarded loads (MLP)
    if (c0 > 1) a1 = bk0[1];
    if (c1 > 0) b0 = bk1[0];
    if (c1 > 1) b1 = bk1[1];
    if (c0 > 0 && p < LCAP) L[p] = a0;
    if (c0 > 1 && p + 1 < LCAP) L[p + 1] = a1;
    for (int j = 2; j < c0; ++j)       // tail: P(c0>2 | lambda=0.5) ~ 1.4%
      if (p + j < LCAP) L[p + j] = bk0[j];
    const int q = p + c0;
    if (c1 > 0 && q < LCAP) L[q] = b0;
    if (c1 > 1 && q + 1 < LCAP) L[q + 1] = b1;
    for (int j = 2; j < c1; ++j)
      if (q + j < LCAP) L[q + j] = bk1[j];
  }
  // no barrier: list[wid] is produced and consumed by this wave only
  // (compiler orders the LDS write->read via lgkmcnt)

  int mm = m < LCAP ? m : LCAP;
  const unsigned short* L = list[wid];
  const unsigned char* z8base = zb8 + sub * 8;

  float acc[8] = {0.f, 0.f, 0.f, 0.f, 0.f, 0.f, 0.f, 0.f};
  for (int e = 0; e < mm; e += 32) {
    // phase 1: issue up to 8 independent 8-B fp8 row loads
    uint2 v[8];
#pragma unroll
    for (int u = 0; u < 8; ++u) {
      int idx = e + u * 4 + g;
      v[u] = make_uint2(0u, 0u);
      if (idx < mm) {
        int s = L[idx];
        v[u] = *(const uint2*)(z8base + (size_t)s * 128);
      }
    }
    // phase 2: packed HW fp8->f32 decode + accumulate (0x00 decodes to 0.0)
#pragma unroll
    for (int u = 0; u < 8; ++u) {
      f32_2 p01 = __builtin_amdgcn_cvt_pk_f32_fp8((int)v[u].x, false);
      f32_2 p23 = __builtin_amdgcn_cvt_pk_f32_fp8((int)v[u].x, true);
      f32_2 p45 = __builtin_amdgcn_cvt_pk_f32_fp8((int)v[u].y, false);
      f32_2 p67 = __builtin_amdgcn_cvt_pk_f32_fp8((int)v[u].y, true);
      acc[0] += p01[0]; acc[1] += p01[1];
      acc[2] += p23[0]; acc[3] += p23[1];
      acc[4] += p45[0]; acc[5] += p45[1];
      acc[6] += p67[0]; acc[7] += p67[1];
    }
  }
#pragma unroll
  for (int k = 0; k < 8; ++k) {
    acc[k] += __shfl_xor(acc[k], 16);
    acc[k] += __shfl_xor(acc[k], 32);
  }

  if (g == 0 && n < N) {
    float inv = 1.f / (float)(m > 0 ? m : 1);
    float r[8];
#pragma unroll
    for (int k = 0; k < 8; ++k) {
      float v2 = acc[k] * inv + (float)zn[k] + bv[k];
      r[k] = v2 > 0.f ? v2 : 0.f;
    }
    float* o2 = out + (size_t)n * 128 + sub * 8;
    *(float4*)(o2)     = make_float4(r[0], r[1], r[2], r[3]);
    *(float4*)(o2 + 4) = make_float4(r[4], r[5], r[6], r[7]);
  }
}

// ---------------------------------------------------------------------------
extern "C" void kernel_launch(void* const* d_in, const int* in_sizes, int n_in,
                              void* d_out, int out_size, void* d_ws, size_t ws_size,
                              hipStream_t stream) {
  const float* x = (const float*)d_in[0];
  const int* ei = (const int*)d_in[1];
  const float* W = (const float*)d_in[2];
  const float* b = (const float*)d_in[3];
  float* out = (float*)d_out;

  const int N = in_sizes[0] / 128;  // 10000
  const int E = in_sizes[1] / 2;    // 640000 (= NB * EPB)

  char* ws = (char*)d_ws;
  size_t off = 0;
  auto carve = [&](size_t bytes) {
    void* p = ws + off;
    off = (off + bytes + 255) & ~(size_t)255;
    return p;
  };
  __hip_bfloat16* zb = (__hip_bfloat16*)carve((size_t)N * 128 * 2);     // 2.56 MB
  unsigned char* zb8 = (unsigned char*)carve((size_t)N * 128);          // 1.28 MB
  unsigned short* bins = (unsigned short*)carve((size_t)NB * EPB * 2);  // 1.28 MB
  unsigned int* combo = (unsigned int*)carve((size_t)NB * NPAD * 4);    // 5.24 MB

  // 1) fused: per-block counting sort (128 blocks, first) || z = x@W^T
  k_phase1<<<NB + NGEMM, 256, 0, stream>>>(x, ei, W, zb, zb8, bins, combo, E);
  // 2) segment-sum + fp8 gather + /deg + z[n] + bias + relu
  k_agg<<<N / 4, 256, 0, stream>>>(combo, bins, zb8, zb, b, out, N);
}